// Round 16
// baseline (89.363 us; speedup 1.0000x reference)
//
#include <hip/hip_runtime.h>
#include <float.h>

#define N_SRC 20000
#define N_TAR 20000
#define TPB 256                    // 4 waves/block
#define SPLITS 16                  // source splits (grid.y)
#define TILES 42                   // 32-source tiles per split; 16*42*32 = 21504 >= 20000
#define PACK_N (SPLITS * TILES * 64)       // 43008 half8 entries (672 KB)
#define TGRP 79                    // 79 blocks * 4 waves * 2 strips * 32 = 20224 targets
#define FBLOCKS ((N_TAR + 255) / 256)

typedef _Float16 half8 __attribute__((ext_vector_type(8)));
typedef float floatx16 __attribute__((ext_vector_type(16)));

// q(t,s) = 0.5||s||^2 - t.s, so 0.5*d2 = 0.5||t||^2 + q (r12-verified split-f16
// slots in mfma_f32_32x32x16_f16; absmax 0 in r12-r15).
// r16: B staged in LDS with TILE-LANE-ORDER layout: pack[tile*64 + L],
// L = half*32 + col. Staging is identity-indexed (coalesced b128 in, b128 out)
// and the K-loop ds_read_b128 is lane-contiguous (lane L -> byte L*16) — the
// m97-verified conflict-free pattern (r13's 1.02e6 conflict cycles came from
// its (col,half)-strided layout). Each tile now hits L2 once per BLOCK (was
// once per wave), and the K-loop reads 12-cyc LDS instead of 250-cyc L2.

#define DPP_MIN(v, ctrl) { \
    const int _s = __builtin_amdgcn_update_dpp( \
        __float_as_int(v), __float_as_int(v), (ctrl), 0xf, 0xf, false); \
    v = fminf(v, __int_as_float(_s)); }
#define COL_REDUCE(v) { \
    DPP_MIN(v, 0xB1)  /* quad_perm xor1 */ \
    DPP_MIN(v, 0x4E)  /* quad_perm xor2 */ \
    DPP_MIN(v, 0x141) /* row_half_mirror */ \
    DPP_MIN(v, 0x140) /* row_mirror */ \
    DPP_MIN(v, 0x142) /* row_bcast15 -> lanes 16-31 hold the 32-col min */ }

// prep: build pack in tile-lane order; zero out[0].
// entry i: tile_lin = i>>6, L = i&63, half = L>>5, s = tile_lin*32 + (L&31)
__global__ __launch_bounds__(TPB) void nn_prep(
    const float* __restrict__ src, half8* __restrict__ pack,
    float* __restrict__ out)
{
    const int i = blockIdx.x * TPB + threadIdx.x;
    if (i == 0) out[0] = 0.f;
    if (i >= PACK_N) return;

    const int L = i & 63;
    const int hf = L >> 5;
    const int s = (i >> 6) * 32 + (L & 31);

    half8 f = {0, 0, 0, 0, 0, 0, 0, 0};
    if (s < N_SRC) {
        const float x = src[s * 3 + 0];
        const float y = src[s * 3 + 1];
        const float z = src[s * 3 + 2];
        const _Float16 xh = (_Float16)x, yh = (_Float16)y, zh = (_Float16)z;
        if (hf == 0) {
            const _Float16 xl = (_Float16)(x - (float)xh);
            const _Float16 yl = (_Float16)(y - (float)yh);
            f = (half8){xh, yh, zh, xh, yh, zh, xl, yl};
        } else {
            const _Float16 zl = (_Float16)(z - (float)zh);
            const float nrm = 0.5f * (x * x + y * y + z * z);
            const _Float16 nh = (_Float16)nrm;
            const _Float16 nl = (_Float16)(nrm - (float)nh);
            f = (half8){zl, nh, nl, 0, 0, 0, 0, 0};
        }
    } else if (hf == 1) {
        f = (half8){0, (_Float16)30000.f, 0, 0, 0, 0, 0, 0};  // pad: never the min
    }
    pack[i] = f;
}

__global__ __launch_bounds__(TPB, 4) void nn_mfma(
    const half8* __restrict__ pack, const float* __restrict__ tar,
    float* __restrict__ part)
{
    __shared__ half8 lds[TILES * 64];   // 42 KB, tile-lane order

    const int tid  = threadIdx.x;
    const int lane = tid & 63;
    const int col  = lane & 31;
    const int half = (lane >> 5) & 1;
    const int wave = tid >> 6;

    // stage this split's tiles: identity-indexed, fully coalesced
    const half8* gp = pack + (size_t)blockIdx.y * (TILES * 64);
    for (int g = tid; g < TILES * 64; g += TPB) lds[g] = pack[(size_t)blockIdx.y * (TILES * 64) + g];
    (void)gp;

    // A fragments in-kernel: this wave's 2 strips of 32 targets
    const int strip0 = (blockIdx.x * 4 + wave) * 2;
    half8 a0, a1;
#pragma unroll
    for (int sidx = 0; sidx < 2; ++sidx) {
        const int t = min((strip0 + sidx) * 32 + col, N_TAR - 1);
        const float tx = tar[t * 3 + 0];
        const float ty = tar[t * 3 + 1];
        const float tz = tar[t * 3 + 2];
        const _Float16 txh = (_Float16)tx, tyh = (_Float16)ty, tzh = (_Float16)tz;
        const _Float16 txl = (_Float16)(tx - (float)txh);
        const _Float16 tyl = (_Float16)(ty - (float)tyh);
        const _Float16 tzl = (_Float16)(tz - (float)tzh);
        half8 a;
        if (half == 0)
            a = (half8){-txh, -tyh, -tzh, -txl, -tyl, -tzl, -txh, -tyh};
        else
            a = (half8){-tzh, (_Float16)1.f, (_Float16)1.f, 0, 0, 0, 0, 0};
        if (sidx == 0) a0 = a; else a1 = a;
    }

    __syncthreads();

    floatx16 m0, m1;
#pragma unroll
    for (int i = 0; i < 16; ++i) { m0[i] = FLT_MAX; m1[i] = FLT_MAX; }
    const floatx16 zero = {};

    // K-loop: register ring of 4 tiles from LDS (lane-contiguous b128 reads)
    const half8* lp = lds + lane;       // per-tile stride = 64 entries
    half8 r0 = lp[0 * 64];
    half8 r1 = lp[1 * 64];
    half8 r2 = lp[2 * 64];
    half8 r3 = lp[3 * 64];
#pragma unroll 1
    for (int tp = 0; tp < TILES; tp += 2) {
        const int nx = min(tp + 4, TILES - 2);   // clamped (dup ok under min)
        const half8 n0 = lp[nx * 64];
        const half8 n1 = lp[nx * 64 + 64];
        {
            const floatx16 d00 = __builtin_amdgcn_mfma_f32_32x32x16_f16(a0, r0, zero, 0, 0, 0);
            const floatx16 d01 = __builtin_amdgcn_mfma_f32_32x32x16_f16(a0, r1, zero, 0, 0, 0);
#pragma unroll
            for (int i = 0; i < 16; ++i) m0[i] = fminf(m0[i], fminf(d00[i], d01[i]));
        }
        {
            const floatx16 d10 = __builtin_amdgcn_mfma_f32_32x32x16_f16(a1, r0, zero, 0, 0, 0);
            const floatx16 d11 = __builtin_amdgcn_mfma_f32_32x32x16_f16(a1, r1, zero, 0, 0, 0);
#pragma unroll
            for (int i = 0; i < 16; ++i) m1[i] = fminf(m1[i], fminf(d10[i], d11[i]));
        }
        r0 = r2; r1 = r3; r2 = n0; r3 = n1;
    }

#pragma unroll
    for (int i = 0; i < 16; ++i) { COL_REDUCE(m0[i]) COL_REDUCE(m1[i]) }

    if (col == 16) {
        float* prow = part + (size_t)blockIdx.y * N_TAR;
#pragma unroll
        for (int i = 0; i < 16; ++i) {
            const int row = (i & 3) + 8 * (i >> 2) + 4 * half;
            const int t0 = min(strip0 * 32 + row, N_TAR - 1);
            const int t1 = min((strip0 + 1) * 32 + row, N_TAR - 1);
            prow[t0] = m0[i];   // clamped rows rewrite identical values: benign
            prow[t1] = m1[i];
        }
    }
}

// combine the SPLITS mins per target, add 0.5||t||^2, reduce into out[0]
__global__ __launch_bounds__(256) void nn_finalize(
    const float* __restrict__ tar, const float* __restrict__ part,
    float* __restrict__ out)
{
    const int t = blockIdx.x * 256 + threadIdx.x;
    float contrib = 0.f;
    if (t < N_TAR) {
        float m = FLT_MAX;
#pragma unroll
        for (int c = 0; c < SPLITS; ++c) m = fminf(m, part[c * N_TAR + t]);
        const float tx = tar[t * 3 + 0];
        const float ty = tar[t * 3 + 1];
        const float tz = tar[t * 3 + 2];
        contrib = 0.5f * (tx * tx + ty * ty + tz * tz) + m;
    }
    for (int off = 32; off > 0; off >>= 1)
        contrib += __shfl_down(contrib, off);
    __shared__ float red[4];
    if ((threadIdx.x & 63) == 0) red[threadIdx.x >> 6] = contrib;
    __syncthreads();
    if (threadIdx.x == 0) {
        float s = 0.f;
#pragma unroll
        for (int w = 0; w < 4; ++w) s += red[w];
        atomicAdd(out, s);
    }
}

extern "C" void kernel_launch(void* const* d_in, const int* in_sizes, int n_in,
                              void* d_out, int out_size, void* d_ws, size_t ws_size,
                              hipStream_t stream) {
    const float* src = (const float*)d_in[0];  // [20000,3] fp32
    const float* tar = (const float*)d_in[1];  // [20000,3] fp32
    float* out = (float*)d_out;                // scalar fp32

    char* w = (char*)d_ws;
    float* part = (float*)w;                           // 16*20000*4 = 1.28 MB
    half8* pack = (half8*)(w + 2 * 1024 * 1024);       // 672 KB

    nn_prep<<<(PACK_N + TPB - 1) / TPB, TPB, 0, stream>>>(src, pack, out);
    dim3 grid1(TGRP, SPLITS);
    nn_mfma<<<grid1, TPB, 0, stream>>>(pack, tar, part);
    nn_finalize<<<FBLOCKS, 256, 0, stream>>>(tar, part, out);
}